// Round 1
// baseline (875.059 us; speedup 1.0000x reference)
//
#include <hip/hip_runtime.h>

// Problem: REN-style forward.
//   L  = strictly-lower(D11)
//   du = u @ D12^T + bv
//   w[i] = tanh( sum_{j<i} L[i,j]*w[j] + du[i] )   (serial in i, parallel in batch)
//   y  = w @ D21^T + u @ D22^T + by
// B=262144, all dims 64, fp32.
//
// Strategy: one thread per batch row. u[64] and w[64] live entirely in VGPRs
// (all loops fully unrolled => constant indices). Matrix elements are read at
// wave-uniform compile-time-constant addresses from const __restrict__
// pointers so the compiler emits s_load (scalar operand folds into
// v_fma_f32). ~14.4K FMAs/thread, compute-bound on the fp32 VALU.

#define NQ 64
#define BATCH 262144

__device__ __forceinline__ float fast_tanh(float x) {
    // tanh(x) = (e^{2x}-1)/(e^{2x}+1); clamp keeps exp finite (tanh(+-20)==+-1 in fp32)
    x = fminf(fmaxf(x, -20.0f), 20.0f);
    float e = __expf(2.0f * x);
    return (e - 1.0f) * __builtin_amdgcn_rcpf(e + 1.0f);
}

__global__ __launch_bounds__(256) void ren_fwd(
    const float* __restrict__ u,
    const float* __restrict__ D11,
    const float* __restrict__ D12,
    const float* __restrict__ D21,
    const float* __restrict__ D22,
    const float* __restrict__ bv,
    const float* __restrict__ by,
    float* __restrict__ out)
{
    const int b = blockIdx.x * blockDim.x + threadIdx.x;
    const float* up = u + (size_t)b * NQ;

    // ---- load u row into registers (16 x float4; rows are 256B so lanes hit
    // 64 distinct lines but the wave's 16KB window stays L1-resident) ----
    float uu[NQ];
#pragma unroll
    for (int j = 0; j < NQ; j += 4) {
        float4 v = *reinterpret_cast<const float4*>(up + j);
        uu[j] = v.x; uu[j+1] = v.y; uu[j+2] = v.z; uu[j+3] = v.w;
    }

    // ---- du phase: w[i] = bv[i] + D12[i,:] . u  (4096 FMA) ----
    float w[NQ];
#pragma unroll
    for (int i = 0; i < NQ; ++i) {
        float acc = bv[i];
#pragma unroll
        for (int j = 0; j < NQ; ++j)
            acc = fmaf(D12[i*NQ + j], uu[j], acc);
        w[i] = acc;
    }

    // ---- triangular recurrence (2080 FMA + 64 tanh), in-place on w ----
#pragma unroll
    for (int i = 0; i < NQ; ++i) {
        float acc = w[i];
#pragma unroll
        for (int j = 0; j < i; ++j)          // strictly lower: j < i
            acc = fmaf(D11[i*NQ + j], w[j], acc);
        w[i] = fast_tanh(acc);
    }

    // ---- output: y[i] = by[i] + D21[i,:].w + D22[i,:].u  (8192 FMA) ----
    float* yp = out + (size_t)b * NQ;
#pragma unroll
    for (int i = 0; i < NQ; i += 4) {
        float acc[4];
#pragma unroll
        for (int k = 0; k < 4; ++k) {
            float a = by[i + k];
#pragma unroll
            for (int j = 0; j < NQ; ++j)
                a = fmaf(D21[(i+k)*NQ + j], w[j], a);
#pragma unroll
            for (int j = 0; j < NQ; ++j)
                a = fmaf(D22[(i+k)*NQ + j], uu[j], a);
            acc[k] = a;
        }
        float4 y4 = make_float4(acc[0], acc[1], acc[2], acc[3]);
        *reinterpret_cast<float4*>(yp + i) = y4;
    }
}

extern "C" void kernel_launch(void* const* d_in, const int* in_sizes, int n_in,
                              void* d_out, int out_size, void* d_ws, size_t ws_size,
                              hipStream_t stream) {
    // setup_inputs order: t(1), xi(B*64), u(B*64), D11, D12, D21, D22, bv, by
    const float* u   = (const float*)d_in[2];
    const float* D11 = (const float*)d_in[3];
    const float* D12 = (const float*)d_in[4];
    const float* D21 = (const float*)d_in[5];
    const float* D22 = (const float*)d_in[6];
    const float* bv  = (const float*)d_in[7];
    const float* by  = (const float*)d_in[8];
    float* out = (float*)d_out;

    ren_fwd<<<BATCH / 256, 256, 0, stream>>>(u, D11, D12, D21, D22, bv, by, out);
}

// Round 2
// 576.502 us; speedup vs baseline: 1.5179x; 1.5179x over previous
//
#include <hip/hip_runtime.h>

// REN-style forward, B=262144, all dims 64, fp32.
//   du = u @ D12^T + bv ; w[i] = tanh(L[i,:j<i].w + du[i]) ; y = w@D21^T + u@D22^T + by
//
// R2: anti-spill restructure. R1 spilled ~1.3KB/thread (WRITE_SIZE 397MB vs
// 66MB output) because uu[64]+w[64] were live through a 14.7K-instr unrolled
// body. Now: peak live ~100 VGPRs, dynamic (unroll-1) outer loops keep each
// straight-line region at 1-2K instr. u is re-read in phase C (L3-resident).
// Recurrence runs column-order for ILP (independent acc updates per step).

#define NQ 64
#define BATCH 262144

__device__ __forceinline__ float fast_tanh(float x) {
    x = fminf(fmaxf(x, -20.0f), 20.0f);
    float e = __expf(2.0f * x);
    return (e - 1.0f) * __builtin_amdgcn_rcpf(e + 1.0f);
}

__global__ __launch_bounds__(256) void ren_fwd(
    const float* __restrict__ u,
    const float* __restrict__ D11,
    const float* __restrict__ D12,
    const float* __restrict__ D21,
    const float* __restrict__ D22,
    const float* __restrict__ bv,
    const float* __restrict__ by,
    float* __restrict__ out)
{
    const int b = blockIdx.x * blockDim.x + threadIdx.x;
    const float* up = u + (size_t)b * NQ;

    // ---- acc[i] starts as bv[i]; becomes du, then w ----
    float acc[NQ];
#pragma unroll
    for (int i = 0; i < NQ; ++i) acc[i] = bv[i];

    // ---- Phase A: acc[i] += D12[i,:] . u, u chunked 16 at a time ----
    // Live: acc[64] + uc[16]. Outer loop NOT unrolled (runtime-uniform jc ->
    // matrix addresses stay wave-uniform -> scalar loads).
#pragma unroll 1
    for (int jc = 0; jc < NQ; jc += 16) {
        float uc[16];
#pragma unroll
        for (int k = 0; k < 16; k += 4) {
            float4 v = *reinterpret_cast<const float4*>(up + jc + k);
            uc[k] = v.x; uc[k+1] = v.y; uc[k+2] = v.z; uc[k+3] = v.w;
        }
        const float* Dp = D12 + jc;
#pragma unroll
        for (int i = 0; i < NQ; ++i) {
            float a = acc[i];
#pragma unroll
            for (int k = 0; k < 16; ++k)
                a = fmaf(Dp[i*NQ + k], uc[k], a);
            acc[i] = a;
        }
    }

    // ---- Phase B: triangular recurrence, COLUMN order for ILP ----
    // After w[j] is known, acc[i] += D11[i,j]*w[j] for all i>j are independent.
    // acc[j] is reused to hold w[j] after its tanh. 2080 FMA + 64 tanh.
#pragma unroll
    for (int j = 0; j < NQ; ++j) {
        float wj = fast_tanh(acc[j]);
        acc[j] = wj;
#pragma unroll
        for (int i = j + 1; i < NQ; ++i)
            acc[i] = fmaf(D11[i*NQ + j], wj, acc[i]);
    }

    // ---- Phase C: y chunked 16 outputs at a time; u re-read per chunk ----
    // Live: acc(w)[64] + yacc[16] + uc[16].
    float* yp = out + (size_t)b * NQ;
#pragma unroll 1
    for (int c = 0; c < NQ; c += 16) {
        float yacc[16];
#pragma unroll
        for (int k = 0; k < 16; ++k) yacc[k] = by[c + k];

        // D21 . w  (w already in registers)
#pragma unroll
        for (int j = 0; j < NQ; ++j) {
            const float wj = acc[j];
#pragma unroll
            for (int k = 0; k < 16; ++k)
                yacc[k] = fmaf(D21[(c + k)*NQ + j], wj, yacc[k]);
        }

        // D22 . u  (u re-loaded 16 at a time; L3-resident)
#pragma unroll 1
        for (int jc = 0; jc < NQ; jc += 16) {
            float uc[16];
#pragma unroll
            for (int k = 0; k < 16; k += 4) {
                float4 v = *reinterpret_cast<const float4*>(up + jc + k);
                uc[k] = v.x; uc[k+1] = v.y; uc[k+2] = v.z; uc[k+3] = v.w;
            }
#pragma unroll
            for (int jj = 0; jj < 16; ++jj) {
                const float uj = uc[jj];
#pragma unroll
                for (int k = 0; k < 16; ++k)
                    yacc[k] = fmaf(D22[(c + k)*NQ + jc + jj], uj, yacc[k]);
            }
        }

#pragma unroll
        for (int k = 0; k < 16; k += 4) {
            float4 y4 = make_float4(yacc[k], yacc[k+1], yacc[k+2], yacc[k+3]);
            *reinterpret_cast<float4*>(yp + c + k) = y4;
        }
    }
}

extern "C" void kernel_launch(void* const* d_in, const int* in_sizes, int n_in,
                              void* d_out, int out_size, void* d_ws, size_t ws_size,
                              hipStream_t stream) {
    // setup_inputs order: t(1), xi, u, D11, D12, D21, D22, bv, by
    const float* u   = (const float*)d_in[2];
    const float* D11 = (const float*)d_in[3];
    const float* D12 = (const float*)d_in[4];
    const float* D21 = (const float*)d_in[5];
    const float* D22 = (const float*)d_in[6];
    const float* bv  = (const float*)d_in[7];
    const float* by  = (const float*)d_in[8];
    float* out = (float*)d_out;

    ren_fwd<<<BATCH / 256, 256, 0, stream>>>(u, D11, D12, D21, D22, bv, by, out);
}

// Round 3
// 357.717 us; speedup vs baseline: 2.4462x; 1.6116x over previous
//
#include <hip/hip_runtime.h>

// REN forward, B=262144, dims 64, fp32.
//   du = u@D12^T + bv ; w[i]=tanh(L(D11)[i,:i].w + du[i]) ; y = w@D21^T + u@D22^T + by
//
// R3: (a) all four matrices staged in LDS (64KB/WG, D11 transposed) --
// uniform-address ds_read_b128 broadcasts replace the s_load path whose
// lgkmcnt stalls capped R2 at 37% VALUBusy; (b) 2 batch rows per thread as
// float2 -> v_pk_fma_f32 halves VALU issue. Column-order recurrence.
// Peak live regs ~210 (acc2[64]=128 + chunk bufs); dynamic outer loops keep
// unrolled regions ~1-5K instr (anti-spill, R1 lesson).

#define NQ 64
#define BATCH 262144

typedef float v2f __attribute__((ext_vector_type(2)));

__device__ __forceinline__ v2f fma2(float m, v2f x, v2f a) {
    return __builtin_elementwise_fma((v2f){m, m}, x, a);
}

__device__ __forceinline__ float fast_tanh(float x) {
    x = fminf(fmaxf(x, -20.0f), 20.0f);
    float e = __expf(2.0f * x);
    return (e - 1.0f) * __builtin_amdgcn_rcpf(e + 1.0f);
}

__device__ __forceinline__ v2f tanh2(v2f x) {
    return (v2f){fast_tanh(x.x), fast_tanh(x.y)};
}

__global__ __launch_bounds__(256) void ren_fwd(
    const float* __restrict__ u,
    const float* __restrict__ D11,
    const float* __restrict__ D12,
    const float* __restrict__ D21,
    const float* __restrict__ D22,
    const float* __restrict__ bv,
    const float* __restrict__ by,
    float* __restrict__ out)
{
    __shared__ __align__(16) float sm[4 * NQ * NQ];   // 64 KB
    float* smD12  = sm;                // [i*64+j] row-major
    float* smD11T = sm + 4096;         // [j*64+i] TRANSPOSED (columns contiguous)
    float* smD21  = sm + 8192;         // row-major
    float* smD22  = sm + 12288;        // row-major

    // ---- cooperative stage: 16 elements per matrix per thread ----
    {
        const int e0 = threadIdx.x * 16;
#pragma unroll
        for (int k = 0; k < 16; k += 4) {
            const int e = e0 + k;
            float4 v;
            v = *reinterpret_cast<const float4*>(D12 + e);
            *reinterpret_cast<float4*>(&smD12[e]) = v;
            v = *reinterpret_cast<const float4*>(D21 + e);
            *reinterpret_cast<float4*>(&smD21[e]) = v;
            v = *reinterpret_cast<const float4*>(D22 + e);
            *reinterpret_cast<float4*>(&smD22[e]) = v;
            v = *reinterpret_cast<const float4*>(D11 + e);
            const int r = e >> 6, c = e & 63;          // row r, cols c..c+3
            smD11T[(c + 0) * NQ + r] = v.x;
            smD11T[(c + 1) * NQ + r] = v.y;
            smD11T[(c + 2) * NQ + r] = v.z;
            smD11T[(c + 3) * NQ + r] = v.w;
        }
    }
    __syncthreads();

    const int t = blockIdx.x * blockDim.x + threadIdx.x;   // row-pair index
    const float* up0 = u + (size_t)(2 * t) * NQ;
    const float* up1 = up0 + NQ;

    // ---- acc2[i] = {bv[i],bv[i]} ; becomes du, then w ----
    v2f acc2[NQ];
#pragma unroll
    for (int i = 0; i < NQ; ++i) { float b = bv[i]; acc2[i] = (v2f){b, b}; }

    // ---- Phase A: acc2[i] += D12[i,:].u  (4096 pk-FMA) ----
#pragma unroll 1
    for (int jc = 0; jc < NQ; jc += 16) {
        v2f uc[16];
#pragma unroll
        for (int k = 0; k < 16; k += 4) {
            float4 a = *reinterpret_cast<const float4*>(up0 + jc + k);
            float4 b = *reinterpret_cast<const float4*>(up1 + jc + k);
            uc[k+0] = (v2f){a.x, b.x}; uc[k+1] = (v2f){a.y, b.y};
            uc[k+2] = (v2f){a.z, b.z}; uc[k+3] = (v2f){a.w, b.w};
        }
        const float* Mp = smD12 + jc;
#pragma unroll
        for (int i = 0; i < NQ; ++i) {
            v2f a = acc2[i];
#pragma unroll
            for (int k = 0; k < 16; k += 4) {
                float4 m4 = *reinterpret_cast<const float4*>(&Mp[i * NQ + k]);
                a = fma2(m4.x, uc[k+0], a);
                a = fma2(m4.y, uc[k+1], a);
                a = fma2(m4.z, uc[k+2], a);
                a = fma2(m4.w, uc[k+3], a);
            }
            acc2[i] = a;
        }
    }

    // ---- Phase B: triangular recurrence, column order (2080 pk-FMA) ----
    // D11 column j is contiguous in smD11T; compile-time j => imm offsets.
#pragma unroll
    for (int j = 0; j < NQ; ++j) {
        v2f wj = tanh2(acc2[j]);
        acc2[j] = wj;
        const int i0 = j + 1;
        const int ia = (i0 + 3) & ~3;
#pragma unroll
        for (int i = i0; i < ia && i < NQ; ++i) {       // scalar head to 16B align
            float m = smD11T[j * NQ + i];
            acc2[i] = fma2(m, wj, acc2[i]);
        }
#pragma unroll
        for (int i = ia; i < NQ; i += 4) {
            float4 m4 = *reinterpret_cast<const float4*>(&smD11T[j * NQ + i]);
            acc2[i+0] = fma2(m4.x, wj, acc2[i+0]);
            acc2[i+1] = fma2(m4.y, wj, acc2[i+1]);
            acc2[i+2] = fma2(m4.z, wj, acc2[i+2]);
            acc2[i+3] = fma2(m4.w, wj, acc2[i+3]);
        }
    }

    // ---- Phase C: y = D21.w + D22.u + by, 16 outputs per chunk (8192 pk-FMA) ----
    float* yp0 = out + (size_t)(2 * t) * NQ;
    float* yp1 = yp0 + NQ;
#pragma unroll 1
    for (int c = 0; c < NQ; c += 16) {
        v2f yacc[16];
#pragma unroll
        for (int k = 0; k < 16; ++k) { float b = by[c + k]; yacc[k] = (v2f){b, b}; }

        // D21 . w (w = acc2, in registers)
#pragma unroll
        for (int k = 0; k < 16; ++k) {
            v2f a = yacc[k];
            const float* Mp = &smD21[(c + k) * NQ];
#pragma unroll
            for (int j = 0; j < NQ; j += 4) {
                float4 m4 = *reinterpret_cast<const float4*>(&Mp[j]);
                a = fma2(m4.x, acc2[j+0], a);
                a = fma2(m4.y, acc2[j+1], a);
                a = fma2(m4.z, acc2[j+2], a);
                a = fma2(m4.w, acc2[j+3], a);
            }
            yacc[k] = a;
        }

        // D22 . u (u re-read; L1/L2-resident)
#pragma unroll 1
        for (int jc = 0; jc < NQ; jc += 16) {
            v2f uc[16];
#pragma unroll
            for (int k = 0; k < 16; k += 4) {
                float4 a = *reinterpret_cast<const float4*>(up0 + jc + k);
                float4 b = *reinterpret_cast<const float4*>(up1 + jc + k);
                uc[k+0] = (v2f){a.x, b.x}; uc[k+1] = (v2f){a.y, b.y};
                uc[k+2] = (v2f){a.z, b.z}; uc[k+3] = (v2f){a.w, b.w};
            }
#pragma unroll
            for (int k = 0; k < 16; ++k) {
                v2f a = yacc[k];
                const float* Mp = &smD22[(c + k) * NQ + jc];
#pragma unroll
                for (int jj = 0; jj < 16; jj += 4) {
                    float4 m4 = *reinterpret_cast<const float4*>(&Mp[jj]);
                    a = fma2(m4.x, uc[jj+0], a);
                    a = fma2(m4.y, uc[jj+1], a);
                    a = fma2(m4.z, uc[jj+2], a);
                    a = fma2(m4.w, uc[jj+3], a);
                }
                yacc[k] = a;
            }
        }

#pragma unroll
        for (int k = 0; k < 16; k += 4) {
            float4 y0 = make_float4(yacc[k].x, yacc[k+1].x, yacc[k+2].x, yacc[k+3].x);
            float4 y1 = make_float4(yacc[k].y, yacc[k+1].y, yacc[k+2].y, yacc[k+3].y);
            *reinterpret_cast<float4*>(yp0 + c + k) = y0;
            *reinterpret_cast<float4*>(yp1 + c + k) = y1;
        }
    }
}

extern "C" void kernel_launch(void* const* d_in, const int* in_sizes, int n_in,
                              void* d_out, int out_size, void* d_ws, size_t ws_size,
                              hipStream_t stream) {
    // setup_inputs order: t(1), xi, u, D11, D12, D21, D22, bv, by
    const float* u   = (const float*)d_in[2];
    const float* D11 = (const float*)d_in[3];
    const float* D12 = (const float*)d_in[4];
    const float* D21 = (const float*)d_in[5];
    const float* D22 = (const float*)d_in[6];
    const float* bv  = (const float*)d_in[7];
    const float* by  = (const float*)d_in[8];
    float* out = (float*)d_out;

    ren_fwd<<<(BATCH / 2) / 256, 256, 0, stream>>>(u, D11, D12, D21, D22, bv, by, out);
}

// Round 4
// 209.856 us; speedup vs baseline: 4.1698x; 1.7046x over previous
//
#include <hip/hip_runtime.h>

// REN forward, B=262144, dims 64, fp32 in/out.
//   du = u@D12^T + bv ; w[i]=tanh(tril(D11,-1)[i,:].w + du[i]) ; y = w@D21^T + u@D22^T + by
//
// R4: MFMA for the two GEMM phases (88% of FLOPs); fp32 VALU only for the
// triangular recurrence. R3 was LDS-pipe-bound (every wave re-read all 16K
// matrix elems; ~6x DS oversubscription). MFMA fragments fetch 16B/lane and
// feed 4 MFMAs of math. Layout: X[256 rows][128 cols] bf16 in LDS = [w|u],
// XOR-swizzled in 16B units by row&7 (frag reads hit the 8-round data limit,
// no bank conflicts). du/w cross phase boundaries as bf16 (err ~2e-3, tol
// 0.0156). D11^T staged fp32 with upper+diag pre-zeroed -> maskless
// recurrence with uniform broadcast reads.

#define NQ 64
#define BATCH 262144
#define RT 256                 // rows per workgroup
#define NWG (BATCH / RT)       // 1024

typedef short bf16x8 __attribute__((ext_vector_type(8)));
typedef float f32x4 __attribute__((ext_vector_type(4)));
typedef unsigned short u16x4 __attribute__((ext_vector_type(4)));

__device__ __forceinline__ unsigned short f2bf(float f) {
    union { float f; unsigned int u; } v; v.f = f;
    unsigned int r = (v.u + 0x7fffu + ((v.u >> 16) & 1u)) >> 16;   // RNE
    return (unsigned short)r;
}
__device__ __forceinline__ float bf2f(unsigned short h) {
    union { unsigned int u; float f; } v; v.u = ((unsigned int)h) << 16;
    return v.f;
}
__device__ __forceinline__ float fast_tanh(float x) {
    x = fminf(fmaxf(x, -20.0f), 20.0f);
    float e = __expf(2.0f * x);
    return (e - 1.0f) * __builtin_amdgcn_rcpf(e + 1.0f);
}
// Swizzled short-index into X[row][col]: 16B units XORed by row&7.
// row in [0,256), col in [0,128). Alignment preserved for any access that
// stays within one 8-short unit (b32/b64/b128 at col%granule==0).
__device__ __forceinline__ int sidx(int row, int col) {
    return row * 128 + ((((col >> 3) ^ (row & 7))) << 3) + (col & 7);
}

__device__ __forceinline__ bf16x8 pack8(float4 a, float4 b) {
    bf16x8 r;
    r[0] = (short)f2bf(a.x); r[1] = (short)f2bf(a.y);
    r[2] = (short)f2bf(a.z); r[3] = (short)f2bf(a.w);
    r[4] = (short)f2bf(b.x); r[5] = (short)f2bf(b.y);
    r[6] = (short)f2bf(b.z); r[7] = (short)f2bf(b.w);
    return r;
}

__global__ __launch_bounds__(256, 2) void ren_fused(
    const float* __restrict__ u,
    const float* __restrict__ D11,
    const float* __restrict__ D12,
    const float* __restrict__ D21,
    const float* __restrict__ D22,
    const float* __restrict__ bv,
    const float* __restrict__ by,
    float* __restrict__ out)
{
    __shared__ __align__(16) unsigned short Xs[RT * 128];   // 64 KB: cols 0-63 = du/w, 64-127 = u (bf16)
    __shared__ __align__(16) float D11Ts[NQ * NQ];          // 16 KB: D11T[j][i] = D11[i][j] if i>j else 0

    const int tid  = threadIdx.x;
    const int lane = tid & 63;
    const int wv   = tid >> 6;        // wave 0..3
    const int ln15 = lane & 15;
    const int kg   = lane >> 4;       // 0..3
    const int wrow0 = wv * 64;        // wave's 64-row slice of the tile
    const size_t R0 = (size_t)blockIdx.x * RT;

    // ================= stage u -> X cols 64..127 (bf16, swizzled) =========
#pragma unroll
    for (int c = 0; c < 16; ++c) {
        const int f   = c * 1024 + tid * 4;       // flat elem in WG's 256x64 u tile
        const int row = f >> 6, col = f & 63;     // col % 4 == 0 (within one unit)
        float4 v = *reinterpret_cast<const float4*>(u + R0 * 64 + f);
        u16x4 h = { f2bf(v.x), f2bf(v.y), f2bf(v.z), f2bf(v.w) };
        *reinterpret_cast<u16x4*>(&Xs[sidx(row, 64 + col)]) = h;
    }
    // ================= stage D11^T (fp32, tril(-1), upper zeroed) ==========
#pragma unroll
    for (int q = 0; q < 4; ++q) {
        const int e = tid * 16 + q * 4;
        const int i = e >> 6, j0 = e & 63;        // D11[i][j0..j0+3]
        float4 v = *reinterpret_cast<const float4*>(D11 + e);
        D11Ts[(j0 + 0) * NQ + i] = (i > j0 + 0) ? v.x : 0.0f;
        D11Ts[(j0 + 1) * NQ + i] = (i > j0 + 1) ? v.y : 0.0f;
        D11Ts[(j0 + 2) * NQ + i] = (i > j0 + 2) ? v.z : 0.0f;
        D11Ts[(j0 + 3) * NQ + i] = (i > j0 + 3) ? v.w : 0.0f;
    }
    __syncthreads();

    // ================= Phase A: du^T = D12 @ u^T (MFMA) ====================
    // D[m=i][n=row]; A-frag = D12[i][k] (global/L2 + cvt), B-frag = u[row][k] (LDS).
    {
        bf16x8 af[4][2];
#pragma unroll
        for (int mt = 0; mt < 4; ++mt)
#pragma unroll
            for (int kt = 0; kt < 2; ++kt) {
                const float* p = D12 + (mt * 16 + ln15) * NQ + kt * 32 + kg * 8;
                af[mt][kt] = pack8(*reinterpret_cast<const float4*>(p),
                                   *reinterpret_cast<const float4*>(p + 4));
            }
        f32x4 acc[4][4];                            // [mt][nt]
#pragma unroll
        for (int mt = 0; mt < 4; ++mt) {
            float4 b4 = *reinterpret_cast<const float4*>(bv + mt * 16 + kg * 4);
#pragma unroll
            for (int nt = 0; nt < 4; ++nt)
                acc[mt][nt] = (f32x4){b4.x, b4.y, b4.z, b4.w};
        }
#pragma unroll
        for (int nt = 0; nt < 4; ++nt) {
            const int row = wrow0 + nt * 16 + ln15;
#pragma unroll
            for (int kt = 0; kt < 2; ++kt) {
                bf16x8 bf = *reinterpret_cast<const bf16x8*>(
                    &Xs[sidx(row, 64 + kt * 32 + kg * 8)]);
#pragma unroll
                for (int mt = 0; mt < 4; ++mt)
                    acc[mt][nt] = __builtin_amdgcn_mfma_f32_16x16x32_bf16(
                        af[mt][kt], bf, acc[mt][nt], 0, 0, 0);
            }
        }
        // write du (bf16) to X cols 0..63. C-layout: i = mt*16+kg*4+reg (contig),
        // row = wrow0 + nt*16 + ln15  -> one u16x4 per (mt,nt).
#pragma unroll
        for (int mt = 0; mt < 4; ++mt)
#pragma unroll
            for (int nt = 0; nt < 4; ++nt) {
                const int row = wrow0 + nt * 16 + ln15;
                const int i0  = mt * 16 + kg * 4;   // i0 % 8 in {0,4}: one unit
                u16x4 h = { f2bf(acc[mt][nt][0]), f2bf(acc[mt][nt][1]),
                            f2bf(acc[mt][nt][2]), f2bf(acc[mt][nt][3]) };
                *reinterpret_cast<u16x4*>(&Xs[sidx(row, i0)]) = h;
            }
    }
    __syncthreads();

    // ================= Phase B: triangular recurrence (fp32 VALU) ==========
    // 1 row per thread. Maskless: D11Ts rows are zero at i<=j, so boundary
    // quads and already-final w slots are never corrupted.
    {
        const int r = tid;
        float a[NQ];
#pragma unroll
        for (int c = 0; c < 8; ++c) {
            bf16x8 h = *reinterpret_cast<const bf16x8*>(&Xs[sidx(r, c * 8)]);
#pragma unroll
            for (int e = 0; e < 8; ++e)
                a[c * 8 + e] = bf2f((unsigned short)h[e]);
        }
#pragma unroll
        for (int j = 0; j < NQ; ++j) {
            const float wj = fast_tanh(a[j]);
            a[j] = wj;
            const int c0 = (j + 1) >> 2;
#pragma unroll
            for (int c = c0; c < 16; ++c) {         // uniform broadcast b128
                float4 d = *reinterpret_cast<const float4*>(&D11Ts[j * NQ + c * 4]);
                a[c * 4 + 0] = fmaf(d.x, wj, a[c * 4 + 0]);
                a[c * 4 + 1] = fmaf(d.y, wj, a[c * 4 + 1]);
                a[c * 4 + 2] = fmaf(d.z, wj, a[c * 4 + 2]);
                a[c * 4 + 3] = fmaf(d.w, wj, a[c * 4 + 3]);
            }
        }
        // write w back as bf16 into X cols 0..63
#pragma unroll
        for (int c = 0; c < 16; ++c) {
            u16x4 h = { f2bf(a[c * 4 + 0]), f2bf(a[c * 4 + 1]),
                        f2bf(a[c * 4 + 2]), f2bf(a[c * 4 + 3]) };
            *reinterpret_cast<u16x4*>(&Xs[sidx(r, c * 4)]) = h;
        }
    }
    __syncthreads();

    // ================= Phase C: y = [w|u] @ [D21|D22]^T (MFMA) =============
    // D[m=row][n=i]; A-frag = X[row][k] (LDS), B-frag = Dcat[i][k] (global/L2).
    {
        bf16x8 af[4][4];
#pragma unroll
        for (int mt = 0; mt < 4; ++mt)
#pragma unroll
            for (int kt = 0; kt < 4; ++kt)
                af[mt][kt] = *reinterpret_cast<const bf16x8*>(
                    &Xs[sidx(wrow0 + mt * 16 + ln15, kt * 32 + kg * 8)]);

        f32x4 yac[4][4];                            // [mt][nt]
#pragma unroll
        for (int nt = 0; nt < 4; ++nt) {
            const float b = by[nt * 16 + ln15];     // col = i depends on ln15 only
#pragma unroll
            for (int mt = 0; mt < 4; ++mt)
                yac[mt][nt] = (f32x4){b, b, b, b};
        }
#pragma unroll
        for (int nt = 0; nt < 4; ++nt)
#pragma unroll
            for (int kt = 0; kt < 4; ++kt) {
                const int i = nt * 16 + ln15;
                const float* p = (kt < 2)
                    ? (D21 + i * NQ + kt * 32 + kg * 8)
                    : (D22 + i * NQ + (kt - 2) * 32 + kg * 8);
                bf16x8 bf = pack8(*reinterpret_cast<const float4*>(p),
                                  *reinterpret_cast<const float4*>(p + 4));
#pragma unroll
                for (int mt = 0; mt < 4; ++mt)
                    yac[mt][nt] = __builtin_amdgcn_mfma_f32_16x16x32_bf16(
                        af[mt][kt], bf, yac[mt][nt], 0, 0, 0);
            }
        // store y: row = R0+wrow0+mt*16+kg*4+reg, col = nt*16+ln15
#pragma unroll
        for (int mt = 0; mt < 4; ++mt) {
            const size_t row = R0 + wrow0 + mt * 16 + kg * 4;
#pragma unroll
            for (int nt = 0; nt < 4; ++nt) {
                const int colI = nt * 16 + ln15;
                out[(row + 0) * NQ + colI] = yac[mt][nt][0];
                out[(row + 1) * NQ + colI] = yac[mt][nt][1];
                out[(row + 2) * NQ + colI] = yac[mt][nt][2];
                out[(row + 3) * NQ + colI] = yac[mt][nt][3];
            }
        }
    }
}

extern "C" void kernel_launch(void* const* d_in, const int* in_sizes, int n_in,
                              void* d_out, int out_size, void* d_ws, size_t ws_size,
                              hipStream_t stream) {
    // setup_inputs order: t(1), xi, u, D11, D12, D21, D22, bv, by
    const float* u   = (const float*)d_in[2];
    const float* D11 = (const float*)d_in[3];
    const float* D12 = (const float*)d_in[4];
    const float* D21 = (const float*)d_in[5];
    const float* D22 = (const float*)d_in[6];
    const float* bv  = (const float*)d_in[7];
    const float* by  = (const float*)d_in[8];
    float* out = (float*)d_out;

    ren_fused<<<NWG, 256, 0, stream>>>(u, D11, D12, D21, D22, bv, by, out);
}